// Round 1
// baseline (340.063 us; speedup 1.0000x reference)
//
#include <hip/hip_runtime.h>

typedef unsigned short u16;
typedef __bf16 bf16x8 __attribute__((ext_vector_type(8)));
typedef float f32x4 __attribute__((ext_vector_type(4)));

// B=16, C=512, H*W=N=1024, groups=32 (16 ch/group)

__device__ __forceinline__ u16 f2bf(float f) {
  union { float f; unsigned u; } v; v.f = f;
  return (u16)((v.u + 0x7fffu + ((v.u >> 16) & 1u)) >> 16);
}

__device__ __forceinline__ f32x4 mfma16(bf16x8 a, bf16x8 b, f32x4 c) {
  return __builtin_amdgcn_mfma_f32_16x16x32_bf16(a, b, c, 0, 0, 0);
}

// ---------------- GroupNorm stats: one block per (b,g); group chunk is contiguous 16384 floats
__global__ __launch_bounds__(256) void gn_stats(const float* __restrict__ x,
                                                float* __restrict__ mean,
                                                float* __restrict__ rstd) {
  int bg = blockIdx.x;
  const float4* p = (const float4*)(x + (size_t)bg * 16384);
  float s = 0.f, ss = 0.f;
  for (int i = threadIdx.x; i < 4096; i += 256) {
    float4 v = p[i];
    s  += v.x + v.y + v.z + v.w;
    ss += v.x*v.x + v.y*v.y + v.z*v.z + v.w*v.w;
  }
  for (int d = 32; d; d >>= 1) { s += __shfl_down(s, d); ss += __shfl_down(ss, d); }
  __shared__ float ls[4], lss[4];
  int wave = threadIdx.x >> 6;
  if ((threadIdx.x & 63) == 0) { ls[wave] = s; lss[wave] = ss; }
  __syncthreads();
  if (threadIdx.x == 0) {
    s = ls[0] + ls[1] + ls[2] + ls[3];
    ss = lss[0] + lss[1] + lss[2] + lss[3];
    float m = s * (1.f / 16384.f);
    float var = ss * (1.f / 16384.f) - m * m;
    mean[bg] = m;
    rstd[bg] = rsqrtf(var + 1e-6f);
  }
}

// ---------------- float -> bf16 cast (weights)
__global__ __launch_bounds__(256) void cast_bf16(const float* __restrict__ src,
                                                 u16* __restrict__ dst, int n) {
  int i = (blockIdx.x * 256 + threadIdx.x) * 4;
  if (i < n) {
    float4 v = *(const float4*)(src + i);
    dst[i] = f2bf(v.x); dst[i+1] = f2bf(v.y); dst[i+2] = f2bf(v.z); dst[i+3] = f2bf(v.w);
  }
}

// ---------------- GroupNorm apply + transpose to h[bn][c] bf16 (K-contiguous for QKV GEMM)
__global__ __launch_bounds__(256) void gn_apply(const float* __restrict__ x,
                                                const float* __restrict__ mean,
                                                const float* __restrict__ rstd,
                                                const float* __restrict__ gw,
                                                const float* __restrict__ gb,
                                                u16* __restrict__ h) {
  __shared__ u16 tile[64][72];
  int b = blockIdx.z, c0 = blockIdx.y * 64, n0 = blockIdx.x * 64;
  int t = threadIdx.x;
  int cc = t >> 2, ns = (t & 3) * 16;
  int c = c0 + cc, g = c >> 4;
  float m = mean[b * 32 + g], r = rstd[b * 32 + g];
  float w = gw[c] * r;
  float bb = gb[c] - m * w;
  const float* xr = x + (((size_t)(b * 512 + c)) << 10) + n0 + ns;
#pragma unroll
  for (int u = 0; u < 16; u += 4) {
    float4 v = *(const float4*)(xr + u);
    tile[cc][ns + u + 0] = f2bf(v.x * w + bb);
    tile[cc][ns + u + 1] = f2bf(v.y * w + bb);
    tile[cc][ns + u + 2] = f2bf(v.z * w + bb);
    tile[cc][ns + u + 3] = f2bf(v.w * w + bb);
  }
  __syncthreads();
  int nn = t >> 2, cs = (t & 3) * 16;
  u16* hr = h + (((size_t)(b * 1024 + n0 + nn)) << 9) + c0 + cs;
  u16 vals[16];
#pragma unroll
  for (int u = 0; u < 16; u++) vals[u] = tile[cs + u][nn];
  *(uint4*)hr = *(uint4*)vals;
  *(uint4*)(hr + 8) = *(uint4*)(vals + 8);
}

// ---------------- 128x128x512 GEMM: C[m][n] = sum_k A[m][k]*Bn[n][k]  (both K-contiguous)
// QKV: A=wq[1536][512], Bn=h[16384][512] -> qkv[o][bn] bf16 (+bias)
__global__ __launch_bounds__(256) void gemm_qkv(const u16* __restrict__ A,
                                                const u16* __restrict__ Bn,
                                                const float* __restrict__ bias,
                                                u16* __restrict__ Cout) {
  __shared__ u16 sA[128][40];
  __shared__ u16 sB[128][40];
  int m0 = blockIdx.y * 128, n0 = blockIdx.x * 128;
  int t = threadIdx.x, wave = t >> 6, lane = t & 63;
  int wm = wave >> 1, wn = wave & 1;
  int col = lane & 15, rowq = lane >> 4;
  f32x4 acc[4][4];
#pragma unroll
  for (int i = 0; i < 4; i++)
#pragma unroll
    for (int j = 0; j < 4; j++) acc[i][j] = (f32x4){0.f, 0.f, 0.f, 0.f};

  for (int k0 = 0; k0 < 512; k0 += 32) {
    __syncthreads();
    {
      int l = t;
      int row = l >> 2, seg = (l & 3) << 3;
      *(uint4*)&sA[row][seg] = *(const uint4*)(A + (size_t)(m0 + row) * 512 + k0 + seg);
      *(uint4*)&sB[row][seg] = *(const uint4*)(Bn + (size_t)(n0 + row) * 512 + k0 + seg);
      l = t + 256;
      row = l >> 2; seg = (l & 3) << 3;
      *(uint4*)&sA[row][seg] = *(const uint4*)(A + (size_t)(m0 + row) * 512 + k0 + seg);
      *(uint4*)&sB[row][seg] = *(const uint4*)(Bn + (size_t)(n0 + row) * 512 + k0 + seg);
    }
    __syncthreads();
    bf16x8 af[4], bfr[4];
#pragma unroll
    for (int i = 0; i < 4; i++) af[i] = *(const bf16x8*)&sA[wm * 64 + i * 16 + col][rowq * 8];
#pragma unroll
    for (int j = 0; j < 4; j++) bfr[j] = *(const bf16x8*)&sB[wn * 64 + j * 16 + col][rowq * 8];
#pragma unroll
    for (int i = 0; i < 4; i++)
#pragma unroll
      for (int j = 0; j < 4; j++) acc[i][j] = mfma16(af[i], bfr[j], acc[i][j]);
  }
#pragma unroll
  for (int i = 0; i < 4; i++)
#pragma unroll
    for (int j = 0; j < 4; j++)
#pragma unroll
      for (int r = 0; r < 4; r++) {
        int o = m0 + wm * 64 + i * 16 + rowq * 4 + r;
        int bn = n0 + wn * 64 + j * 16 + col;
        Cout[(size_t)o * 16384 + bn] = f2bf(acc[i][j][r] + bias[o]);
      }
}

// ---------------- transpose qkv rows o<1024 into q_nc[bn][c], k_nc[bn][c]
__global__ __launch_bounds__(256) void transpose_qk(const u16* __restrict__ qkvT,
                                                    u16* __restrict__ q_nc,
                                                    u16* __restrict__ k_nc) {
  __shared__ u16 tile[64][72];
  int o0 = blockIdx.y * 64, bn0 = blockIdx.x * 64;
  int t = threadIdx.x;
  int r = t >> 2, s0 = (t & 3) * 16;
  const u16* src = qkvT + (size_t)(o0 + r) * 16384 + bn0 + s0;
  *(uint4*)&tile[r][s0] = *(const uint4*)src;
  *(uint4*)&tile[r][s0 + 8] = *(const uint4*)(src + 8);
  __syncthreads();
  int rr = t >> 2, cs = (t & 3) * 16;
  u16* dst = (o0 < 512 ? q_nc : k_nc) + (size_t)(bn0 + rr) * 512 + (o0 & 511) + cs;
  u16 vals[16];
#pragma unroll
  for (int u = 0; u < 16; u++) vals[u] = tile[cs + u][rr];
  *(uint4*)dst = *(uint4*)vals;
  *(uint4*)(dst + 8) = *(uint4*)(vals + 8);
}

// ---------------- fused attention per (b, 16 q-rows): S=Q.K^T (frags direct from global),
// register softmax with cross-wave LDS reduce, P bf16 in LDS, O^T = P.V -> o_nc[bn][c]
__global__ __launch_bounds__(256) void attn_kernel(const u16* __restrict__ q_nc,
                                                   const u16* __restrict__ k_nc,
                                                   const u16* __restrict__ v,
                                                   u16* __restrict__ o_nc) {
  __shared__ u16 P[16][1032];          // pad 8: b128 reads stay at 8-lane/slot baseline
  __shared__ float red[2][4][16];
  int b = blockIdx.y, i0 = blockIdx.x * 16;
  int t = threadIdx.x, wave = t >> 6, lane = t & 63;
  int col = lane & 15, rowq = lane >> 4;
  const u16* qb = q_nc + (((size_t)(b * 1024 + i0)) << 9);
  const u16* kb = k_nc + (((size_t)(b * 1024 + wave * 256)) << 9);

  f32x4 s[16];
#pragma unroll
  for (int nf = 0; nf < 16; nf++) s[nf] = (f32x4){0.f, 0.f, 0.f, 0.f};

  for (int kc = 0; kc < 16; kc++) {
    bf16x8 af = *(const bf16x8*)(qb + (col << 9) + kc * 32 + rowq * 8);
#pragma unroll
    for (int nf = 0; nf < 16; nf++) {
      bf16x8 bfr = *(const bf16x8*)(kb + (((size_t)(nf * 16 + col)) << 9) + kc * 32 + rowq * 8);
      s[nf] = mfma16(af, bfr, s[nf]);
    }
  }

  const float scale = 0.04419417382415922f;  // 512^-0.5
  float mx[4], sm[4], gm[4];
#pragma unroll
  for (int nf = 0; nf < 16; nf++)
#pragma unroll
    for (int r = 0; r < 4; r++) s[nf][r] *= scale;

#pragma unroll
  for (int r = 0; r < 4; r++) {
    float m = -1e30f;
#pragma unroll
    for (int nf = 0; nf < 16; nf++) m = fmaxf(m, s[nf][r]);
    mx[r] = m;
  }
#pragma unroll
  for (int r = 0; r < 4; r++)
    for (int d = 1; d < 16; d <<= 1) mx[r] = fmaxf(mx[r], __shfl_xor(mx[r], d));
  if (col == 0) {
#pragma unroll
    for (int r = 0; r < 4; r++) red[0][wave][rowq * 4 + r] = mx[r];
  }
  __syncthreads();
#pragma unroll
  for (int r = 0; r < 4; r++) {
    int row = rowq * 4 + r;
    gm[r] = fmaxf(fmaxf(red[0][0][row], red[0][1][row]),
                  fmaxf(red[0][2][row], red[0][3][row]));
    sm[r] = 0.f;
  }
#pragma unroll
  for (int nf = 0; nf < 16; nf++)
#pragma unroll
    for (int r = 0; r < 4; r++) {
      float e = __expf(s[nf][r] - gm[r]);
      s[nf][r] = e;
      sm[r] += e;
    }
#pragma unroll
  for (int r = 0; r < 4; r++)
    for (int d = 1; d < 16; d <<= 1) sm[r] += __shfl_xor(sm[r], d);
  if (col == 0) {
#pragma unroll
    for (int r = 0; r < 4; r++) red[1][wave][rowq * 4 + r] = sm[r];
  }
  __syncthreads();
#pragma unroll
  for (int r = 0; r < 4; r++) {
    int row = rowq * 4 + r;
    float tot = red[1][0][row] + red[1][1][row] + red[1][2][row] + red[1][3][row];
    gm[r] = 1.f / tot;
  }
  int j0w = wave * 256;
#pragma unroll
  for (int nf = 0; nf < 16; nf++)
#pragma unroll
    for (int r = 0; r < 4; r++)
      P[rowq * 4 + r][j0w + nf * 16 + col] = f2bf(s[nf][r] * gm[r]);
  __syncthreads();

  // PV: O^T[i][c] = sum_j P[i][j] * v[c][j]; wave owns 128-channel chunk
  f32x4 oacc[8];
#pragma unroll
  for (int nf = 0; nf < 8; nf++) oacc[nf] = (f32x4){0.f, 0.f, 0.f, 0.f};
  int c0w = wave * 128;
  for (int kc = 0; kc < 32; kc++) {
    bf16x8 pa = *(const bf16x8*)&P[col][kc * 32 + rowq * 8];
#pragma unroll
    for (int nf = 0; nf < 8; nf++) {
      const u16* vp = v + (size_t)(c0w + nf * 16 + col) * 16384 + (b << 10) + kc * 32 + rowq * 8;
      bf16x8 vf = *(const bf16x8*)vp;
      oacc[nf] = mfma16(pa, vf, oacc[nf]);
    }
  }
#pragma unroll
  for (int nf = 0; nf < 8; nf++)
#pragma unroll
    for (int r = 0; r < 4; r++)
      o_nc[(((size_t)(b * 1024 + i0 + rowq * 4 + r)) << 9) + c0w + nf * 16 + col] =
          f2bf(oacc[nf][r]);
}

// ---------------- proj GEMM + bias + residual -> fp32 out[b][co][n]
__global__ __launch_bounds__(256) void gemm_proj(const u16* __restrict__ A,
                                                 const u16* __restrict__ Bn,
                                                 const float* __restrict__ bias,
                                                 const float* __restrict__ xres,
                                                 float* __restrict__ outp) {
  __shared__ u16 sA[128][40];
  __shared__ u16 sB[128][40];
  int m0 = blockIdx.y * 128, n0 = blockIdx.x * 128;
  int t = threadIdx.x, wave = t >> 6, lane = t & 63;
  int wm = wave >> 1, wn = wave & 1;
  int col = lane & 15, rowq = lane >> 4;
  f32x4 acc[4][4];
#pragma unroll
  for (int i = 0; i < 4; i++)
#pragma unroll
    for (int j = 0; j < 4; j++) acc[i][j] = (f32x4){0.f, 0.f, 0.f, 0.f};

  for (int k0 = 0; k0 < 512; k0 += 32) {
    __syncthreads();
    {
      int l = t;
      int row = l >> 2, seg = (l & 3) << 3;
      *(uint4*)&sA[row][seg] = *(const uint4*)(A + (size_t)(m0 + row) * 512 + k0 + seg);
      *(uint4*)&sB[row][seg] = *(const uint4*)(Bn + (size_t)(n0 + row) * 512 + k0 + seg);
      l = t + 256;
      row = l >> 2; seg = (l & 3) << 3;
      *(uint4*)&sA[row][seg] = *(const uint4*)(A + (size_t)(m0 + row) * 512 + k0 + seg);
      *(uint4*)&sB[row][seg] = *(const uint4*)(Bn + (size_t)(n0 + row) * 512 + k0 + seg);
    }
    __syncthreads();
    bf16x8 af[4], bfr[4];
#pragma unroll
    for (int i = 0; i < 4; i++) af[i] = *(const bf16x8*)&sA[wm * 64 + i * 16 + col][rowq * 8];
#pragma unroll
    for (int j = 0; j < 4; j++) bfr[j] = *(const bf16x8*)&sB[wn * 64 + j * 16 + col][rowq * 8];
#pragma unroll
    for (int i = 0; i < 4; i++)
#pragma unroll
      for (int j = 0; j < 4; j++) acc[i][j] = mfma16(af[i], bfr[j], acc[i][j]);
  }
#pragma unroll
  for (int i = 0; i < 4; i++)
#pragma unroll
    for (int j = 0; j < 4; j++)
#pragma unroll
      for (int r = 0; r < 4; r++) {
        int co = m0 + wm * 64 + i * 16 + rowq * 4 + r;
        int bn = n0 + wn * 64 + j * 16 + col;
        int bb = bn >> 10, n = bn & 1023;
        size_t oi = (((size_t)(bb * 512 + co)) << 10) + n;
        outp[oi] = acc[i][j][r] + bias[co] + xres[oi];
      }
}

extern "C" void kernel_launch(void* const* d_in, const int* in_sizes, int n_in,
                              void* d_out, int out_size, void* d_ws, size_t ws_size,
                              hipStream_t stream) {
  const float* x      = (const float*)d_in[0];
  const float* norm_w = (const float*)d_in[1];
  const float* norm_b = (const float*)d_in[2];
  const float* qkv_w  = (const float*)d_in[3];
  const float* qkv_b  = (const float*)d_in[4];
  const float* proj_w = (const float*)d_in[5];
  const float* proj_b = (const float*)d_in[6];
  float* out = (float*)d_out;

  char* ws = (char*)d_ws;
  size_t off = 0;
  auto alloc = [&](size_t bytes) {
    void* p = ws + off;
    off += (bytes + 255) & ~(size_t)255;
    return p;
  };
  float* mean = (float*)alloc(512 * 4);
  float* rstd = (float*)alloc(512 * 4);
  u16* wq   = (u16*)alloc((size_t)1536 * 512 * 2);
  u16* wp   = (u16*)alloc((size_t)512 * 512 * 2);
  u16* h    = (u16*)alloc((size_t)16384 * 512 * 2);   // reused as o_nc after QKV GEMM
  u16* qkvT = (u16*)alloc((size_t)1536 * 16384 * 2);
  u16* q_nc = (u16*)alloc((size_t)16384 * 512 * 2);
  u16* k_nc = (u16*)alloc((size_t)16384 * 512 * 2);
  u16* o_nc = h;
  (void)in_sizes; (void)n_in; (void)out_size; (void)ws_size;

  gn_stats<<<512, 256, 0, stream>>>(x, mean, rstd);
  cast_bf16<<<(1536 * 512) / 1024, 256, 0, stream>>>(qkv_w, wq, 1536 * 512);
  cast_bf16<<<(512 * 512) / 1024, 256, 0, stream>>>(proj_w, wp, 512 * 512);
  gn_apply<<<dim3(16, 8, 16), 256, 0, stream>>>(x, mean, rstd, norm_w, norm_b, h);
  gemm_qkv<<<dim3(128, 12), 256, 0, stream>>>(wq, h, qkv_b, qkvT);
  transpose_qk<<<dim3(256, 16), 256, 0, stream>>>(qkvT, q_nc, k_nc);
  attn_kernel<<<dim3(64, 16), 256, 0, stream>>>(q_nc, k_nc, qkvT + (size_t)1024 * 16384, o_nc);
  gemm_proj<<<dim3(128, 4), 256, 0, stream>>>(wp, o_nc, proj_b, x, out);
}

// Round 2
// 173.110 us; speedup vs baseline: 1.9644x; 1.9644x over previous
//
#include <hip/hip_runtime.h>

typedef unsigned short u16;
typedef __bf16 bf16x8 __attribute__((ext_vector_type(8)));
typedef float f32x4 __attribute__((ext_vector_type(4)));

// B=16, C=512, N=H*W=1024, groups=32 (16 ch/group)

__device__ __forceinline__ u16 f2bf(float f) {
  union { float f; unsigned u; } v; v.f = f;
  return (u16)((v.u + 0x7fffu + ((v.u >> 16) & 1u)) >> 16);
}

__device__ __forceinline__ f32x4 mfma16(bf16x8 a, bf16x8 b, f32x4 c) {
  return __builtin_amdgcn_mfma_f32_16x16x32_bf16(a, b, c, 0, 0, 0);
}

// ---------------- GroupNorm stats: one block per (b,g); contiguous 16384 floats
__global__ __launch_bounds__(256) void gn_stats(const float* __restrict__ x,
                                                float* __restrict__ mean,
                                                float* __restrict__ rstd) {
  int bg = blockIdx.x;
  const float4* p = (const float4*)(x + (size_t)bg * 16384);
  float s = 0.f, ss = 0.f;
  for (int i = threadIdx.x; i < 4096; i += 256) {
    float4 v = p[i];
    s  += v.x + v.y + v.z + v.w;
    ss += v.x*v.x + v.y*v.y + v.z*v.z + v.w*v.w;
  }
  for (int d = 32; d; d >>= 1) { s += __shfl_down(s, d); ss += __shfl_down(ss, d); }
  __shared__ float ls[4], lss[4];
  int wave = threadIdx.x >> 6;
  if ((threadIdx.x & 63) == 0) { ls[wave] = s; lss[wave] = ss; }
  __syncthreads();
  if (threadIdx.x == 0) {
    s = ls[0] + ls[1] + ls[2] + ls[3];
    ss = lss[0] + lss[1] + lss[2] + lss[3];
    float m = s * (1.f / 16384.f);
    float var = ss * (1.f / 16384.f) - m * m;
    mean[bg] = m;
    rstd[bg] = rsqrtf(var + 1e-6f);
  }
}

// ---------------- float -> bf16 cast (weights)
__global__ __launch_bounds__(256) void cast_bf16(const float* __restrict__ src,
                                                 u16* __restrict__ dst, int n) {
  int i = (blockIdx.x * 256 + threadIdx.x) * 4;
  if (i < n) {
    float4 v = *(const float4*)(src + i);
    dst[i] = f2bf(v.x); dst[i+1] = f2bf(v.y); dst[i+2] = f2bf(v.z); dst[i+3] = f2bf(v.w);
  }
}

// ---------------- GroupNorm apply + transpose to h[bn][c] bf16
__global__ __launch_bounds__(256) void gn_apply(const float* __restrict__ x,
                                                const float* __restrict__ mean,
                                                const float* __restrict__ rstd,
                                                const float* __restrict__ gw,
                                                const float* __restrict__ gb,
                                                u16* __restrict__ h) {
  __shared__ u16 tile[64][72];
  int b = blockIdx.z, c0 = blockIdx.y * 64, n0 = blockIdx.x * 64;
  int t = threadIdx.x;
  int cc = t >> 2, ns = (t & 3) * 16;
  int c = c0 + cc, g = c >> 4;
  float m = mean[b * 32 + g], r = rstd[b * 32 + g];
  float w = gw[c] * r;
  float bb = gb[c] - m * w;
  const float* xr = x + (((size_t)(b * 512 + c)) << 10) + n0 + ns;
#pragma unroll
  for (int u = 0; u < 16; u += 4) {
    float4 v = *(const float4*)(xr + u);
    tile[cc][ns + u + 0] = f2bf(v.x * w + bb);
    tile[cc][ns + u + 1] = f2bf(v.y * w + bb);
    tile[cc][ns + u + 2] = f2bf(v.z * w + bb);
    tile[cc][ns + u + 3] = f2bf(v.w * w + bb);
  }
  __syncthreads();
  int nn = t >> 2, cs = (t & 3) * 16;
  u16* hr = h + (((size_t)(b * 1024 + n0 + nn)) << 9) + c0 + cs;
  u16 vals[16];
#pragma unroll
  for (int u = 0; u < 16; u++) vals[u] = tile[cs + u][nn];
  *(uint4*)hr = *(uint4*)vals;
  *(uint4*)(hr + 8) = *(uint4*)(vals + 8);
}

// ---------------- QKV GEMM: A=wq[1536][512], Bn=h[16384][512]
// writes q_nc[bn][512], k_nc[bn][512] (transposed epilogue), v[c][16384]
__global__ __launch_bounds__(256) void gemm_qkv(const u16* __restrict__ A,
                                                const u16* __restrict__ Bn,
                                                const float* __restrict__ bias,
                                                u16* __restrict__ q_nc,
                                                u16* __restrict__ k_nc,
                                                u16* __restrict__ v) {
  __shared__ u16 sA[128][40];
  __shared__ u16 sB[128][40];
  int m0 = blockIdx.y * 128, n0 = blockIdx.x * 128;
  int t = threadIdx.x, wave = t >> 6, lane = t & 63;
  int wm = wave >> 1, wn = wave & 1;
  int col = lane & 15, rowq = lane >> 4;
  f32x4 acc[4][4];
#pragma unroll
  for (int i = 0; i < 4; i++)
#pragma unroll
    for (int j = 0; j < 4; j++) acc[i][j] = (f32x4){0.f, 0.f, 0.f, 0.f};

  for (int k0 = 0; k0 < 512; k0 += 32) {
    __syncthreads();
    {
      int l = t;
      int row = l >> 2, seg = (l & 3) << 3;
      *(uint4*)&sA[row][seg] = *(const uint4*)(A + (size_t)(m0 + row) * 512 + k0 + seg);
      *(uint4*)&sB[row][seg] = *(const uint4*)(Bn + (size_t)(n0 + row) * 512 + k0 + seg);
      l = t + 256;
      row = l >> 2; seg = (l & 3) << 3;
      *(uint4*)&sA[row][seg] = *(const uint4*)(A + (size_t)(m0 + row) * 512 + k0 + seg);
      *(uint4*)&sB[row][seg] = *(const uint4*)(Bn + (size_t)(n0 + row) * 512 + k0 + seg);
    }
    __syncthreads();
    bf16x8 af[4], bfr[4];
#pragma unroll
    for (int i = 0; i < 4; i++) af[i] = *(const bf16x8*)&sA[wm * 64 + i * 16 + col][rowq * 8];
#pragma unroll
    for (int j = 0; j < 4; j++) bfr[j] = *(const bf16x8*)&sB[wn * 64 + j * 16 + col][rowq * 8];
#pragma unroll
    for (int i = 0; i < 4; i++)
#pragma unroll
      for (int j = 0; j < 4; j++) acc[i][j] = mfma16(af[i], bfr[j], acc[i][j]);
  }
  int mb = blockIdx.y;
  if (mb < 8) {
    u16* dst = (mb < 4) ? q_nc : k_nc;
#pragma unroll
    for (int i = 0; i < 4; i++)
#pragma unroll
      for (int j = 0; j < 4; j++) {
        int o = m0 + wm * 64 + i * 16 + rowq * 4;
        int bn = n0 + wn * 64 + j * 16 + col;
        u16 tmp[4];
#pragma unroll
        for (int r = 0; r < 4; r++) tmp[r] = f2bf(acc[i][j][r] + bias[o + r]);
        *(uint2*)(dst + (size_t)bn * 512 + (o & 511)) = *(uint2*)tmp;
      }
  } else {
#pragma unroll
    for (int i = 0; i < 4; i++)
#pragma unroll
      for (int j = 0; j < 4; j++)
#pragma unroll
        for (int r = 0; r < 4; r++) {
          int o = m0 + wm * 64 + i * 16 + rowq * 4 + r;
          int bn = n0 + wn * 64 + j * 16 + col;
          v[(size_t)(o & 511) * 16384 + bn] = f2bf(acc[i][j][r] + bias[o]);
        }
  }
}

// ---------------- S GEMM per b: S[i][j] = scale * sum_c q[i][c]*k[j][c], f32 out
__global__ __launch_bounds__(256) void gemm_s(const u16* __restrict__ q_nc,
                                              const u16* __restrict__ k_nc,
                                              float* __restrict__ S) {
  __shared__ u16 sA[128][40];
  __shared__ u16 sB[128][40];
  int bid = blockIdx.x;               // 1024 blocks, XCD-swizzled: 2 b per XCD
  int xcd = bid & 7, r2 = bid >> 3;
  int b = xcd * 2 + (r2 & 1);
  int tile = r2 >> 1;                 // 64 = 8 ib x 8 jb
  int m0 = (tile >> 3) * 128, n0 = (tile & 7) * 128;
  const u16* A  = q_nc + ((size_t)b << 10) * 512;
  const u16* Bn = k_nc + ((size_t)b << 10) * 512;
  int t = threadIdx.x, wave = t >> 6, lane = t & 63;
  int wm = wave >> 1, wn = wave & 1;
  int col = lane & 15, rowq = lane >> 4;
  f32x4 acc[4][4];
#pragma unroll
  for (int i = 0; i < 4; i++)
#pragma unroll
    for (int j = 0; j < 4; j++) acc[i][j] = (f32x4){0.f, 0.f, 0.f, 0.f};

  for (int k0 = 0; k0 < 512; k0 += 32) {
    __syncthreads();
    {
      int l = t;
      int row = l >> 2, seg = (l & 3) << 3;
      *(uint4*)&sA[row][seg] = *(const uint4*)(A + (size_t)(m0 + row) * 512 + k0 + seg);
      *(uint4*)&sB[row][seg] = *(const uint4*)(Bn + (size_t)(n0 + row) * 512 + k0 + seg);
      l = t + 256;
      row = l >> 2; seg = (l & 3) << 3;
      *(uint4*)&sA[row][seg] = *(const uint4*)(A + (size_t)(m0 + row) * 512 + k0 + seg);
      *(uint4*)&sB[row][seg] = *(const uint4*)(Bn + (size_t)(n0 + row) * 512 + k0 + seg);
    }
    __syncthreads();
    bf16x8 af[4], bfr[4];
#pragma unroll
    for (int i = 0; i < 4; i++) af[i] = *(const bf16x8*)&sA[wm * 64 + i * 16 + col][rowq * 8];
#pragma unroll
    for (int j = 0; j < 4; j++) bfr[j] = *(const bf16x8*)&sB[wn * 64 + j * 16 + col][rowq * 8];
#pragma unroll
    for (int i = 0; i < 4; i++)
#pragma unroll
      for (int j = 0; j < 4; j++) acc[i][j] = mfma16(af[i], bfr[j], acc[i][j]);
  }
  float* Sb = S + ((size_t)b << 20);
  const float scale = 0.04419417382415922f;  // 512^-0.5
#pragma unroll
  for (int i = 0; i < 4; i++)
#pragma unroll
    for (int j = 0; j < 4; j++) {
      int ii = m0 + wm * 64 + i * 16 + rowq * 4;
      int jj = n0 + wn * 64 + j * 16 + col;
#pragma unroll
      for (int r = 0; r < 4; r++) Sb[(size_t)(ii + r) * 1024 + jj] = acc[i][j][r] * scale;
    }
}

// ---------------- row softmax: S f32 [16384][1024] -> P bf16, one wave per row
__global__ __launch_bounds__(256) void softmax_rows(const float* __restrict__ S,
                                                    u16* __restrict__ P) {
  int row = blockIdx.x * 4 + (threadIdx.x >> 6);
  int lane = threadIdx.x & 63;
  const float* sr = S + (size_t)row * 1024;
  float4 v[4];
  float m = -1e30f;
#pragma unroll
  for (int u = 0; u < 4; u++) {
    v[u] = *(const float4*)(sr + u * 256 + lane * 4);
    m = fmaxf(m, fmaxf(fmaxf(v[u].x, v[u].y), fmaxf(v[u].z, v[u].w)));
  }
#pragma unroll
  for (int d = 1; d < 64; d <<= 1) m = fmaxf(m, __shfl_xor(m, d));
  float e[16];
  float sum = 0.f;
#pragma unroll
  for (int u = 0; u < 4; u++) {
    e[u*4+0] = __expf(v[u].x - m); e[u*4+1] = __expf(v[u].y - m);
    e[u*4+2] = __expf(v[u].z - m); e[u*4+3] = __expf(v[u].w - m);
    sum += e[u*4+0] + e[u*4+1] + e[u*4+2] + e[u*4+3];
  }
#pragma unroll
  for (int d = 1; d < 64; d <<= 1) sum += __shfl_xor(sum, d);
  float inv = 1.f / sum;
  u16* pr = P + (size_t)row * 1024;
#pragma unroll
  for (int u = 0; u < 4; u++) {
    u16 tmp[4] = {f2bf(e[u*4+0]*inv), f2bf(e[u*4+1]*inv), f2bf(e[u*4+2]*inv), f2bf(e[u*4+3]*inv)};
    *(uint2*)(pr + u * 256 + lane * 4) = *(uint2*)tmp;
  }
}

// ---------------- PV GEMM per b: O[i][c] = sum_j P[i][j] * v[c][j] -> o_nc[bn][c]
__global__ __launch_bounds__(256) void gemm_pv(const u16* __restrict__ P,
                                               const u16* __restrict__ v,
                                               u16* __restrict__ o_nc) {
  __shared__ u16 sA[128][40];
  __shared__ u16 sB[128][40];
  int bid = blockIdx.x;               // 512 blocks, XCD-swizzled
  int xcd = bid & 7, r2 = bid >> 3;
  int b = xcd * 2 + (r2 & 1);
  int tile = r2 >> 1;                 // 32 = 8 ib x 4 cb
  int m0 = (tile >> 2) * 128, n0 = (tile & 3) * 128;
  const u16* A = P + ((size_t)b << 10) * 1024;
  int t = threadIdx.x, wave = t >> 6, lane = t & 63;
  int wm = wave >> 1, wn = wave & 1;
  int col = lane & 15, rowq = lane >> 4;
  f32x4 acc[4][4];
#pragma unroll
  for (int i = 0; i < 4; i++)
#pragma unroll
    for (int j = 0; j < 4; j++) acc[i][j] = (f32x4){0.f, 0.f, 0.f, 0.f};

  for (int k0 = 0; k0 < 1024; k0 += 32) {
    __syncthreads();
    {
      int l = t;
      int row = l >> 2, seg = (l & 3) << 3;
      *(uint4*)&sA[row][seg] = *(const uint4*)(A + (size_t)(m0 + row) * 1024 + k0 + seg);
      *(uint4*)&sB[row][seg] = *(const uint4*)(v + (size_t)(n0 + row) * 16384 + (b << 10) + k0 + seg);
      l = t + 256;
      row = l >> 2; seg = (l & 3) << 3;
      *(uint4*)&sA[row][seg] = *(const uint4*)(A + (size_t)(m0 + row) * 1024 + k0 + seg);
      *(uint4*)&sB[row][seg] = *(const uint4*)(v + (size_t)(n0 + row) * 16384 + (b << 10) + k0 + seg);
    }
    __syncthreads();
    bf16x8 af[4], bfr[4];
#pragma unroll
    for (int i = 0; i < 4; i++) af[i] = *(const bf16x8*)&sA[wm * 64 + i * 16 + col][rowq * 8];
#pragma unroll
    for (int j = 0; j < 4; j++) bfr[j] = *(const bf16x8*)&sB[wn * 64 + j * 16 + col][rowq * 8];
#pragma unroll
    for (int i = 0; i < 4; i++)
#pragma unroll
      for (int j = 0; j < 4; j++) acc[i][j] = mfma16(af[i], bfr[j], acc[i][j]);
  }
#pragma unroll
  for (int i = 0; i < 4; i++)
#pragma unroll
    for (int j = 0; j < 4; j++)
#pragma unroll
      for (int r = 0; r < 4; r++) {
        int ii = m0 + wm * 64 + i * 16 + rowq * 4 + r;
        int cc = n0 + wn * 64 + j * 16 + col;
        o_nc[(((size_t)(b * 1024 + ii)) << 9) + cc] = f2bf(acc[i][j][r]);
      }
}

// ---------------- proj GEMM + bias + residual -> fp32 out[b][co][n]
__global__ __launch_bounds__(256) void gemm_proj(const u16* __restrict__ A,
                                                 const u16* __restrict__ Bn,
                                                 const float* __restrict__ bias,
                                                 const float* __restrict__ xres,
                                                 float* __restrict__ outp) {
  __shared__ u16 sA[128][40];
  __shared__ u16 sB[128][40];
  int m0 = blockIdx.y * 128, n0 = blockIdx.x * 128;
  int t = threadIdx.x, wave = t >> 6, lane = t & 63;
  int wm = wave >> 1, wn = wave & 1;
  int col = lane & 15, rowq = lane >> 4;
  f32x4 acc[4][4];
#pragma unroll
  for (int i = 0; i < 4; i++)
#pragma unroll
    for (int j = 0; j < 4; j++) acc[i][j] = (f32x4){0.f, 0.f, 0.f, 0.f};

  for (int k0 = 0; k0 < 512; k0 += 32) {
    __syncthreads();
    {
      int l = t;
      int row = l >> 2, seg = (l & 3) << 3;
      *(uint4*)&sA[row][seg] = *(const uint4*)(A + (size_t)(m0 + row) * 512 + k0 + seg);
      *(uint4*)&sB[row][seg] = *(const uint4*)(Bn + (size_t)(n0 + row) * 512 + k0 + seg);
      l = t + 256;
      row = l >> 2; seg = (l & 3) << 3;
      *(uint4*)&sA[row][seg] = *(const uint4*)(A + (size_t)(m0 + row) * 512 + k0 + seg);
      *(uint4*)&sB[row][seg] = *(const uint4*)(Bn + (size_t)(n0 + row) * 512 + k0 + seg);
    }
    __syncthreads();
    bf16x8 af[4], bfr[4];
#pragma unroll
    for (int i = 0; i < 4; i++) af[i] = *(const bf16x8*)&sA[wm * 64 + i * 16 + col][rowq * 8];
#pragma unroll
    for (int j = 0; j < 4; j++) bfr[j] = *(const bf16x8*)&sB[wn * 64 + j * 16 + col][rowq * 8];
#pragma unroll
    for (int i = 0; i < 4; i++)
#pragma unroll
      for (int j = 0; j < 4; j++) acc[i][j] = mfma16(af[i], bfr[j], acc[i][j]);
  }
#pragma unroll
  for (int i = 0; i < 4; i++)
#pragma unroll
    for (int j = 0; j < 4; j++)
#pragma unroll
      for (int r = 0; r < 4; r++) {
        int co = m0 + wm * 64 + i * 16 + rowq * 4 + r;
        int bn = n0 + wn * 64 + j * 16 + col;
        int bb = bn >> 10, n = bn & 1023;
        size_t oi = (((size_t)(bb * 512 + co)) << 10) + n;
        outp[oi] = acc[i][j][r] + bias[co] + xres[oi];
      }
}

extern "C" void kernel_launch(void* const* d_in, const int* in_sizes, int n_in,
                              void* d_out, int out_size, void* d_ws, size_t ws_size,
                              hipStream_t stream) {
  const float* x      = (const float*)d_in[0];
  const float* norm_w = (const float*)d_in[1];
  const float* norm_b = (const float*)d_in[2];
  const float* qkv_w  = (const float*)d_in[3];
  const float* qkv_b  = (const float*)d_in[4];
  const float* proj_w = (const float*)d_in[5];
  const float* proj_b = (const float*)d_in[6];
  float* out = (float*)d_out;

  char* ws = (char*)d_ws;
  size_t off = 0;
  auto alloc = [&](size_t bytes) {
    void* p = ws + off;
    off += (bytes + 255) & ~(size_t)255;
    return p;
  };
  float* mean = (float*)alloc(512 * 4);
  float* rstd = (float*)alloc(512 * 4);
  u16* wq   = (u16*)alloc((size_t)1536 * 512 * 2);
  u16* wp   = (u16*)alloc((size_t)512 * 512 * 2);
  u16* h    = (u16*)alloc((size_t)16384 * 512 * 2);   // reused as o_nc after QKV GEMM
  u16* q_nc = (u16*)alloc((size_t)16384 * 512 * 2);   // reused (with k_nc) as P after gemm_s
  u16* k_nc = (u16*)alloc((size_t)16384 * 512 * 2);
  u16* v    = (u16*)alloc((size_t)512 * 16384 * 2);
  float* S  = (float*)alloc((size_t)16 * 1024 * 1024 * 4);
  u16* P    = q_nc;   // 32 MB overlay on q_nc+k_nc (dead after gemm_s)
  u16* o_nc = h;
  (void)in_sizes; (void)n_in; (void)out_size; (void)ws_size; (void)k_nc;

  gn_stats<<<512, 256, 0, stream>>>(x, mean, rstd);
  cast_bf16<<<(1536 * 512) / 1024, 256, 0, stream>>>(qkv_w, wq, 1536 * 512);
  cast_bf16<<<(512 * 512) / 1024, 256, 0, stream>>>(proj_w, wp, 512 * 512);
  gn_apply<<<dim3(16, 8, 16), 256, 0, stream>>>(x, mean, rstd, norm_w, norm_b, h);
  gemm_qkv<<<dim3(128, 12), 256, 0, stream>>>(wq, h, qkv_b, q_nc, k_nc, v);
  gemm_s<<<1024, 256, 0, stream>>>(q_nc, k_nc, S);
  softmax_rows<<<4096, 256, 0, stream>>>(S, P);
  gemm_pv<<<512, 256, 0, stream>>>(P, v, o_nc);
  gemm_proj<<<dim3(128, 4), 256, 0, stream>>>(wp, o_nc, proj_b, x, out);
}

// Round 3
// 153.114 us; speedup vs baseline: 2.2210x; 1.1306x over previous
//
#include <hip/hip_runtime.h>

typedef unsigned short u16;
typedef __bf16 bf16x8 __attribute__((ext_vector_type(8)));
typedef float f32x4 __attribute__((ext_vector_type(4)));

// B=16, C=512, N=H*W=1024, groups=32 (16 ch/group)

__device__ __forceinline__ u16 f2bf(float f) {
  union { float f; unsigned u; } v; v.f = f;
  return (u16)((v.u + 0x7fffu + ((v.u >> 16) & 1u)) >> 16);
}

__device__ __forceinline__ float bf2f(u16 x) {
  union { unsigned u; float f; } v; v.u = ((unsigned)x) << 16; return v.f;
}

__device__ __forceinline__ f32x4 mfma16(bf16x8 a, bf16x8 b, f32x4 c) {
  return __builtin_amdgcn_mfma_f32_16x16x32_bf16(a, b, c, 0, 0, 0);
}

// ---- global->LDS DMA staging of a 128x32 u16 tile (linear LDS, XOR seg-swizzle on source)
// LDS loc (row, qloc) holds global chunk (row, qloc ^ ((row>>1)&3)); reader applies same XOR.
__device__ __forceinline__ void stage_tile(const u16* __restrict__ src, size_t ld,
                                           u16* lds, int wv, int lane) {
#pragma unroll
  for (int h2 = 0; h2 < 2; h2++) {
    int rbase = wv * 32 + h2 * 16;
    int row = rbase + (lane >> 2);
    int segd = (lane & 3) ^ ((row >> 1) & 3);
    __builtin_amdgcn_global_load_lds(
        (const __attribute__((address_space(1))) void*)(src + (size_t)row * ld + segd * 8),
        (__attribute__((address_space(3))) void*)(lds + rbase * 32),
        16, 0, 0);
  }
}

__device__ __forceinline__ bf16x8 ldsfrag(const u16* lds, int row, int rowq) {
  int q = rowq ^ ((row >> 1) & 3);
  return *(const bf16x8*)(lds + row * 32 + q * 8);
}

// ---------------- GroupNorm stats: one block per (b,g); contiguous 16384 floats
__global__ __launch_bounds__(256) void gn_stats(const float* __restrict__ x,
                                                float* __restrict__ mean,
                                                float* __restrict__ rstd) {
  int bg = blockIdx.x;
  const float4* p = (const float4*)(x + (size_t)bg * 16384);
  float s = 0.f, ss = 0.f;
  for (int i = threadIdx.x; i < 4096; i += 256) {
    float4 v = p[i];
    s  += v.x + v.y + v.z + v.w;
    ss += v.x*v.x + v.y*v.y + v.z*v.z + v.w*v.w;
  }
  for (int d = 32; d; d >>= 1) { s += __shfl_down(s, d); ss += __shfl_down(ss, d); }
  __shared__ float ls[4], lss[4];
  int wave = threadIdx.x >> 6;
  if ((threadIdx.x & 63) == 0) { ls[wave] = s; lss[wave] = ss; }
  __syncthreads();
  if (threadIdx.x == 0) {
    s = ls[0] + ls[1] + ls[2] + ls[3];
    ss = lss[0] + lss[1] + lss[2] + lss[3];
    float m = s * (1.f / 16384.f);
    float var = ss * (1.f / 16384.f) - m * m;
    mean[bg] = m;
    rstd[bg] = rsqrtf(var + 1e-6f);
  }
}

// ---------------- float -> bf16 cast (weights)
__global__ __launch_bounds__(256) void cast_bf16(const float* __restrict__ src,
                                                 u16* __restrict__ dst, int n) {
  int i = (blockIdx.x * 256 + threadIdx.x) * 4;
  if (i < n) {
    float4 v = *(const float4*)(src + i);
    dst[i] = f2bf(v.x); dst[i+1] = f2bf(v.y); dst[i+2] = f2bf(v.z); dst[i+3] = f2bf(v.w);
  }
}

// ---------------- GroupNorm apply + transpose to h[bn][c] bf16
__global__ __launch_bounds__(256) void gn_apply(const float* __restrict__ x,
                                                const float* __restrict__ mean,
                                                const float* __restrict__ rstd,
                                                const float* __restrict__ gw,
                                                const float* __restrict__ gb,
                                                u16* __restrict__ h) {
  __shared__ u16 tile[64][72];
  int b = blockIdx.z, c0 = blockIdx.y * 64, n0 = blockIdx.x * 64;
  int t = threadIdx.x;
  int cc = t >> 2, ns = (t & 3) * 16;
  int c = c0 + cc, g = c >> 4;
  float m = mean[b * 32 + g], r = rstd[b * 32 + g];
  float w = gw[c] * r;
  float bb = gb[c] - m * w;
  const float* xr = x + (((size_t)(b * 512 + c)) << 10) + n0 + ns;
#pragma unroll
  for (int u = 0; u < 16; u += 4) {
    float4 v = *(const float4*)(xr + u);
    tile[cc][ns + u + 0] = f2bf(v.x * w + bb);
    tile[cc][ns + u + 1] = f2bf(v.y * w + bb);
    tile[cc][ns + u + 2] = f2bf(v.z * w + bb);
    tile[cc][ns + u + 3] = f2bf(v.w * w + bb);
  }
  __syncthreads();
  int nn = t >> 2, cs = (t & 3) * 16;
  u16* hr = h + (((size_t)(b * 1024 + n0 + nn)) << 9) + c0 + cs;
  u16 vals[16];
#pragma unroll
  for (int u = 0; u < 16; u++) vals[u] = tile[cs + u][nn];
  *(uint4*)hr = *(uint4*)vals;
  *(uint4*)(hr + 8) = *(uint4*)(vals + 8);
}

// ---------------- QKV GEMM: A=wq[1536][512], Bn=h[16384][512]
// q_nc[bn][512], k_nc[bn][512] (transposed epilogue), v[c][16384]
__global__ __launch_bounds__(256) void gemm_qkv(const u16* __restrict__ A,
                                                const u16* __restrict__ Bn,
                                                const float* __restrict__ bias,
                                                u16* __restrict__ q_nc,
                                                u16* __restrict__ k_nc,
                                                u16* __restrict__ v) {
  __shared__ u16 sA[128 * 32];
  __shared__ u16 sB[128 * 32];
  int bid = blockIdx.x;                     // 1536; XCD n-chunked
  int xcd = bid & 7, r = bid >> 3;          // r 0..191
  int mb = r % 12, nb = xcd * 16 + r / 12;
  int m0 = mb * 128, n0 = nb * 128;
  int t = threadIdx.x, wave = t >> 6, lane = t & 63;
  int wm = wave >> 1, wn = wave & 1;
  int col = lane & 15, rowq = lane >> 4;
  f32x4 acc[4][4];
#pragma unroll
  for (int i = 0; i < 4; i++)
#pragma unroll
    for (int j = 0; j < 4; j++) acc[i][j] = (f32x4){0.f, 0.f, 0.f, 0.f};

  for (int k0 = 0; k0 < 512; k0 += 32) {
    __syncthreads();
    stage_tile(A + (size_t)m0 * 512 + k0, 512, sA, wave, lane);
    stage_tile(Bn + (size_t)n0 * 512 + k0, 512, sB, wave, lane);
    __syncthreads();
    bf16x8 af[4], bfr[4];
#pragma unroll
    for (int i = 0; i < 4; i++) af[i] = ldsfrag(sA, wm * 64 + i * 16 + col, rowq);
#pragma unroll
    for (int j = 0; j < 4; j++) bfr[j] = ldsfrag(sB, wn * 64 + j * 16 + col, rowq);
#pragma unroll
    for (int i = 0; i < 4; i++)
#pragma unroll
      for (int j = 0; j < 4; j++) acc[i][j] = mfma16(af[i], bfr[j], acc[i][j]);
  }
  if (mb < 8) {
    u16* dst = (mb < 4) ? q_nc : k_nc;
#pragma unroll
    for (int i = 0; i < 4; i++)
#pragma unroll
      for (int j = 0; j < 4; j++) {
        int o = m0 + wm * 64 + i * 16 + rowq * 4;
        int bn = n0 + wn * 64 + j * 16 + col;
        u16 tmp[4];
#pragma unroll
        for (int rr = 0; rr < 4; rr++) tmp[rr] = f2bf(acc[i][j][rr] + bias[o + rr]);
        *(uint2*)(dst + (size_t)bn * 512 + (o & 511)) = *(uint2*)tmp;
      }
  } else {
#pragma unroll
    for (int i = 0; i < 4; i++)
#pragma unroll
      for (int j = 0; j < 4; j++)
#pragma unroll
        for (int rr = 0; rr < 4; rr++) {
          int o = m0 + wm * 64 + i * 16 + rowq * 4 + rr;
          int bn = n0 + wn * 64 + j * 16 + col;
          v[(size_t)(o & 511) * 16384 + bn] = f2bf(acc[i][j][rr] + bias[o]);
        }
  }
}

// ---------------- S GEMM per b: E[i][j] = exp(scale * sum_c q[i][c]*k[j][c]) bf16 (max-free)
__global__ __launch_bounds__(256) void gemm_s(const u16* __restrict__ q_nc,
                                              const u16* __restrict__ k_nc,
                                              u16* __restrict__ E) {
  __shared__ u16 sA[128 * 32];
  __shared__ u16 sB[128 * 32];
  int bid = blockIdx.x;               // 1024: 2 b per XCD
  int xcd = bid & 7, r2 = bid >> 3;
  int b = xcd * 2 + (r2 & 1);
  int tile = r2 >> 1;                 // 64 = 8 ib x 8 jb
  int m0 = (tile >> 3) * 128, n0 = (tile & 7) * 128;
  const u16* A  = q_nc + ((size_t)b << 10) * 512;
  const u16* Bn = k_nc + ((size_t)b << 10) * 512;
  int t = threadIdx.x, wave = t >> 6, lane = t & 63;
  int wm = wave >> 1, wn = wave & 1;
  int col = lane & 15, rowq = lane >> 4;
  f32x4 acc[4][4];
#pragma unroll
  for (int i = 0; i < 4; i++)
#pragma unroll
    for (int j = 0; j < 4; j++) acc[i][j] = (f32x4){0.f, 0.f, 0.f, 0.f};

  for (int k0 = 0; k0 < 512; k0 += 32) {
    __syncthreads();
    stage_tile(A + (size_t)m0 * 512 + k0, 512, sA, wave, lane);
    stage_tile(Bn + (size_t)n0 * 512 + k0, 512, sB, wave, lane);
    __syncthreads();
    bf16x8 af[4], bfr[4];
#pragma unroll
    for (int i = 0; i < 4; i++) af[i] = ldsfrag(sA, wm * 64 + i * 16 + col, rowq);
#pragma unroll
    for (int j = 0; j < 4; j++) bfr[j] = ldsfrag(sB, wn * 64 + j * 16 + col, rowq);
#pragma unroll
    for (int i = 0; i < 4; i++)
#pragma unroll
      for (int j = 0; j < 4; j++) acc[i][j] = mfma16(af[i], bfr[j], acc[i][j]);
  }
  u16* Eb = E + ((size_t)b << 20);
  const float scale = 0.04419417382415922f;  // 512^-0.5
#pragma unroll
  for (int i = 0; i < 4; i++)
#pragma unroll
    for (int j = 0; j < 4; j++) {
      int ii = m0 + wm * 64 + i * 16 + rowq * 4;
      int jj = n0 + wn * 64 + j * 16 + col;
#pragma unroll
      for (int rr = 0; rr < 4; rr++)
        Eb[(size_t)(ii + rr) * 1024 + jj] = f2bf(__expf(acc[i][j][rr] * scale));
    }
}

// ---------------- row inverse-sum: inv[row] = 1/sum_j E[row][j]
__global__ __launch_bounds__(256) void row_inv(const u16* __restrict__ E,
                                               float* __restrict__ inv) {
  int row = blockIdx.x * 4 + (threadIdx.x >> 6);
  int lane = threadIdx.x & 63;
  const u16* er = E + (size_t)row * 1024 + lane * 16;
  uint4 a = *(const uint4*)er;
  uint4 c = *(const uint4*)(er + 8);
  float s = 0.f;
  unsigned ws[8] = {a.x, a.y, a.z, a.w, c.x, c.y, c.z, c.w};
#pragma unroll
  for (int u = 0; u < 8; u++) {
    union { unsigned u; float f; } lo, hi;
    lo.u = ws[u] << 16; hi.u = ws[u] & 0xffff0000u;
    s += lo.f + hi.f;
  }
#pragma unroll
  for (int d = 1; d < 64; d <<= 1) s += __shfl_xor(s, d);
  if (lane == 0) inv[row] = 1.0f / s;
}

// ---------------- PV GEMM per b: O[i][c] = inv[i] * sum_j E[i][j]*v[c][j] -> o_nc[bn][c]
__global__ __launch_bounds__(256) void gemm_pv(const u16* __restrict__ E,
                                               const u16* __restrict__ v,
                                               const float* __restrict__ inv,
                                               u16* __restrict__ o_nc) {
  __shared__ u16 sA[128 * 32];
  __shared__ u16 sB[128 * 32];
  int bid = blockIdx.x;               // 512
  int xcd = bid & 7, r2 = bid >> 3;
  int b = xcd * 2 + (r2 & 1);
  int tile = r2 >> 1;                 // 32 = 8 ib x 4 cb
  int m0 = (tile >> 2) * 128, n0 = (tile & 3) * 128;
  const u16* A = E + ((size_t)b << 20);
  int t = threadIdx.x, wave = t >> 6, lane = t & 63;
  int wm = wave >> 1, wn = wave & 1;
  int col = lane & 15, rowq = lane >> 4;
  f32x4 acc[4][4];
#pragma unroll
  for (int i = 0; i < 4; i++)
#pragma unroll
    for (int j = 0; j < 4; j++) acc[i][j] = (f32x4){0.f, 0.f, 0.f, 0.f};

  for (int k0 = 0; k0 < 1024; k0 += 32) {
    __syncthreads();
    stage_tile(A + (size_t)m0 * 1024 + k0, 1024, sA, wave, lane);
    stage_tile(v + (size_t)n0 * 16384 + ((size_t)b << 10) + k0, 16384, sB, wave, lane);
    __syncthreads();
    bf16x8 af[4], bfr[4];
#pragma unroll
    for (int i = 0; i < 4; i++) af[i] = ldsfrag(sA, wm * 64 + i * 16 + col, rowq);
#pragma unroll
    for (int j = 0; j < 4; j++) bfr[j] = ldsfrag(sB, wn * 64 + j * 16 + col, rowq);
#pragma unroll
    for (int i = 0; i < 4; i++)
#pragma unroll
      for (int j = 0; j < 4; j++) acc[i][j] = mfma16(af[i], bfr[j], acc[i][j]);
  }
#pragma unroll
  for (int i = 0; i < 4; i++)
#pragma unroll
    for (int j = 0; j < 4; j++)
#pragma unroll
      for (int rr = 0; rr < 4; rr++) {
        int ii = m0 + wm * 64 + i * 16 + rowq * 4 + rr;
        int cc = n0 + wn * 64 + j * 16 + col;
        float sc = inv[(b << 10) + ii];
        o_nc[(((size_t)(b * 1024 + ii)) << 9) + cc] = f2bf(acc[i][j][rr] * sc);
      }
}

// ---------------- proj GEMM + bias + residual -> fp32 out[b][co][n]
__global__ __launch_bounds__(256) void gemm_proj(const u16* __restrict__ A,
                                                 const u16* __restrict__ Bn,
                                                 const float* __restrict__ bias,
                                                 const float* __restrict__ xres,
                                                 float* __restrict__ outp) {
  __shared__ u16 sA[128 * 32];
  __shared__ u16 sB[128 * 32];
  int bid = blockIdx.x;                 // 512; XCD n-chunked
  int xcd = bid & 7, r = bid >> 3;      // 0..63
  int mb = r & 3, nb = xcd * 16 + (r >> 2);
  int m0 = mb * 128, n0 = nb * 128;
  int t = threadIdx.x, wave = t >> 6, lane = t & 63;
  int wm = wave >> 1, wn = wave & 1;
  int col = lane & 15, rowq = lane >> 4;
  f32x4 acc[4][4];
#pragma unroll
  for (int i = 0; i < 4; i++)
#pragma unroll
    for (int j = 0; j < 4; j++) acc[i][j] = (f32x4){0.f, 0.f, 0.f, 0.f};

  for (int k0 = 0; k0 < 512; k0 += 32) {
    __syncthreads();
    stage_tile(A + (size_t)m0 * 512 + k0, 512, sA, wave, lane);
    stage_tile(Bn + (size_t)n0 * 512 + k0, 512, sB, wave, lane);
    __syncthreads();
    bf16x8 af[4], bfr[4];
#pragma unroll
    for (int i = 0; i < 4; i++) af[i] = ldsfrag(sA, wm * 64 + i * 16 + col, rowq);
#pragma unroll
    for (int j = 0; j < 4; j++) bfr[j] = ldsfrag(sB, wn * 64 + j * 16 + col, rowq);
#pragma unroll
    for (int i = 0; i < 4; i++)
#pragma unroll
      for (int j = 0; j < 4; j++) acc[i][j] = mfma16(af[i], bfr[j], acc[i][j]);
  }
#pragma unroll
  for (int i = 0; i < 4; i++)
#pragma unroll
    for (int j = 0; j < 4; j++)
#pragma unroll
      for (int rr = 0; rr < 4; rr++) {
        int co = m0 + wm * 64 + i * 16 + rowq * 4 + rr;
        int bn = n0 + wn * 64 + j * 16 + col;
        int bb = bn >> 10, n = bn & 1023;
        size_t oi = (((size_t)(bb * 512 + co)) << 10) + n;
        outp[oi] = acc[i][j][rr] + bias[co] + xres[oi];
      }
}

extern "C" void kernel_launch(void* const* d_in, const int* in_sizes, int n_in,
                              void* d_out, int out_size, void* d_ws, size_t ws_size,
                              hipStream_t stream) {
  const float* x      = (const float*)d_in[0];
  const float* norm_w = (const float*)d_in[1];
  const float* norm_b = (const float*)d_in[2];
  const float* qkv_w  = (const float*)d_in[3];
  const float* qkv_b  = (const float*)d_in[4];
  const float* proj_w = (const float*)d_in[5];
  const float* proj_b = (const float*)d_in[6];
  float* out = (float*)d_out;

  char* ws = (char*)d_ws;
  size_t off = 0;
  auto alloc = [&](size_t bytes) {
    void* p = ws + off;
    off += (bytes + 255) & ~(size_t)255;
    return p;
  };
  float* mean = (float*)alloc(512 * 4);
  float* rstd = (float*)alloc(512 * 4);
  float* inv  = (float*)alloc(16384 * 4);
  u16* wq   = (u16*)alloc((size_t)1536 * 512 * 2);
  u16* wp   = (u16*)alloc((size_t)512 * 512 * 2);
  u16* h    = (u16*)alloc((size_t)16384 * 512 * 2);   // reused as o_nc after QKV GEMM
  u16* q_nc = (u16*)alloc((size_t)16384 * 512 * 2);
  u16* k_nc = (u16*)alloc((size_t)16384 * 512 * 2);
  u16* v    = (u16*)alloc((size_t)512 * 16384 * 2);
  u16* E    = (u16*)alloc((size_t)16 * 1024 * 1024 * 2);
  u16* o_nc = h;
  (void)in_sizes; (void)n_in; (void)out_size; (void)ws_size;

  gn_stats<<<512, 256, 0, stream>>>(x, mean, rstd);
  cast_bf16<<<(1536 * 512) / 1024, 256, 0, stream>>>(qkv_w, wq, 1536 * 512);
  cast_bf16<<<(512 * 512) / 1024, 256, 0, stream>>>(proj_w, wp, 512 * 512);
  gn_apply<<<dim3(16, 8, 16), 256, 0, stream>>>(x, mean, rstd, norm_w, norm_b, h);
  gemm_qkv<<<1536, 256, 0, stream>>>(wq, h, qkv_b, q_nc, k_nc, v);
  gemm_s<<<1024, 256, 0, stream>>>(q_nc, k_nc, E);
  row_inv<<<4096, 256, 0, stream>>>(E, inv);
  gemm_pv<<<512, 256, 0, stream>>>(E, v, inv, o_nc);
  gemm_proj<<<512, 256, 0, stream>>>(wp, o_nc, proj_b, x, out);
}

// Round 4
// 140.425 us; speedup vs baseline: 2.4217x; 1.0904x over previous
//
#include <hip/hip_runtime.h>

typedef unsigned short u16;
typedef __bf16 bf16x8 __attribute__((ext_vector_type(8)));
typedef float f32x4 __attribute__((ext_vector_type(4)));

#define AS1 __attribute__((address_space(1)))
#define AS3 __attribute__((address_space(3)))

// B=16, C=512, N=H*W=1024, groups=32 (16 ch/group)

__device__ __forceinline__ u16 f2bf(float f) {
  union { float f; unsigned u; } v; v.f = f;
  return (u16)((v.u + 0x7fffu + ((v.u >> 16) & 1u)) >> 16);
}

__device__ __forceinline__ f32x4 mfma16(bf16x8 a, bf16x8 b, f32x4 c) {
  return __builtin_amdgcn_mfma_f32_16x16x32_bf16(a, b, c, 0, 0, 0);
}

// ---- stage ROUNDS*64 rows x 64 cols (one K-tile of one matrix) via global_load_lds.
// LDS linear dest; XOR slot-swizzle applied on the per-lane GLOBAL source (rule: both-sides).
// LDS (row, slot) holds global (row, slot ^ (row&7)); reader applies the same XOR.
template<int ROUNDS>
__device__ __forceinline__ void stage_mat(const u16* __restrict__ src, int ld,
                                          u16* lds, int wave, int lane) {
#pragma unroll
  for (int rnd = 0; rnd < ROUNDS; rnd++) {
    int rbase = rnd * 64 + wave * 8;
    int row = rbase + (lane >> 3);
    int slot = (lane & 7) ^ (row & 7);
    __builtin_amdgcn_global_load_lds(
        (const AS1 void*)(src + (size_t)row * ld + slot * 8),
        (AS3 void*)(lds + rbase * 64), 16, 0, 0);
  }
}

// ---- deep-pipelined GEMM core: BM = M_REP*32 (wm in {0,1} owns M_REP 16-row frags),
// BN = 256 (wn in {0..3} owns 4), BK = 64, NT K-tiles. 2 LDS buffers, counted vmcnt.
template<int M_REP, int NT>
__device__ __forceinline__ void gemm_core(const u16* __restrict__ A, int lda,
                                          const u16* __restrict__ B, int ldb,
                                          u16* lds, f32x4 (&acc)[M_REP][4],
                                          int wave, int lane) {
  constexpr int BM = M_REP * 32;
  constexpr int AR = BM / 64;              // A stage rounds (2 or 4)
  constexpr int ATILE = BM * 64;           // u16 per A K-tile
  constexpr int VM = AR + 4;               // loads per K-tile in flight
  u16* sA0 = lds;
  u16* sA1 = lds + ATILE;
  u16* sB0 = lds + 2 * ATILE;
  u16* sB1 = lds + 2 * ATILE + 16384;
  int wm = wave >> 2, wn = wave & 3;
  int col = lane & 15, rq = lane >> 4;
#pragma unroll
  for (int m = 0; m < M_REP; m++)
#pragma unroll
    for (int n = 0; n < 4; n++) acc[m][n] = (f32x4){0.f, 0.f, 0.f, 0.f};

  stage_mat<AR>(A, lda, sA0, wave, lane);
  stage_mat<4>(B, ldb, sB0, wave, lane);
  stage_mat<AR>(A + 64, lda, sA1, wave, lane);
  stage_mat<4>(B + 64, ldb, sB1, wave, lane);

  for (int t = 0; t < NT; t++) {
    u16* cA = (t & 1) ? sA1 : sA0;
    u16* cB = (t & 1) ? sB1 : sB0;
    if (t < NT - 1) {
      asm volatile("s_waitcnt vmcnt(%0)" :: "i"(VM) : "memory");
    } else {
      asm volatile("s_waitcnt vmcnt(0)" ::: "memory");
    }
    __builtin_amdgcn_sched_barrier(0);
    __builtin_amdgcn_s_barrier();
    __builtin_amdgcn_sched_barrier(0);
    __builtin_amdgcn_s_setprio(1);
#pragma unroll
    for (int kk = 0; kk < 2; kk++) {
      bf16x8 bfr[4];
#pragma unroll
      for (int n = 0; n < 4; n++) {
        int row = wn * 64 + n * 16 + col;
        bfr[n] = *(const bf16x8*)(cB + row * 64 + ((kk * 4 + rq) ^ (row & 7)) * 8);
      }
#pragma unroll
      for (int m = 0; m < M_REP; m++) {
        int row = wm * (BM / 2) + m * 16 + col;
        bf16x8 af = *(const bf16x8*)(cA + row * 64 + ((kk * 4 + rq) ^ (row & 7)) * 8);
#pragma unroll
        for (int n = 0; n < 4; n++) acc[m][n] = mfma16(af, bfr[n], acc[m][n]);
      }
    }
    __builtin_amdgcn_s_setprio(0);
    __builtin_amdgcn_sched_barrier(0);
    __builtin_amdgcn_s_barrier();
    if (t + 2 < NT) {
      stage_mat<AR>(A + (size_t)(t + 2) * 64, lda, cA, wave, lane);
      stage_mat<4>(B + (size_t)(t + 2) * 64, ldb, cB, wave, lane);
    }
  }
}

// ---------------- GroupNorm stats
__global__ __launch_bounds__(256) void gn_stats(const float* __restrict__ x,
                                                float* __restrict__ mean,
                                                float* __restrict__ rstd) {
  int bg = blockIdx.x;
  const float4* p = (const float4*)(x + (size_t)bg * 16384);
  float s = 0.f, ss = 0.f;
  for (int i = threadIdx.x; i < 4096; i += 256) {
    float4 v = p[i];
    s  += v.x + v.y + v.z + v.w;
    ss += v.x*v.x + v.y*v.y + v.z*v.z + v.w*v.w;
  }
  for (int d = 32; d; d >>= 1) { s += __shfl_down(s, d); ss += __shfl_down(ss, d); }
  __shared__ float ls[4], lss[4];
  int wave = threadIdx.x >> 6;
  if ((threadIdx.x & 63) == 0) { ls[wave] = s; lss[wave] = ss; }
  __syncthreads();
  if (threadIdx.x == 0) {
    s = ls[0] + ls[1] + ls[2] + ls[3];
    ss = lss[0] + lss[1] + lss[2] + lss[3];
    float m = s * (1.f / 16384.f);
    float var = ss * (1.f / 16384.f) - m * m;
    mean[bg] = m;
    rstd[bg] = rsqrtf(var + 1e-6f);
  }
}

// ---------------- float -> bf16 cast (weights)
__global__ __launch_bounds__(256) void cast_bf16(const float* __restrict__ src,
                                                 u16* __restrict__ dst, int n) {
  int i = (blockIdx.x * 256 + threadIdx.x) * 4;
  if (i < n) {
    float4 v = *(const float4*)(src + i);
    dst[i] = f2bf(v.x); dst[i+1] = f2bf(v.y); dst[i+2] = f2bf(v.z); dst[i+3] = f2bf(v.w);
  }
}

// ---------------- GroupNorm apply + transpose to h[bn][c] bf16
__global__ __launch_bounds__(256) void gn_apply(const float* __restrict__ x,
                                                const float* __restrict__ mean,
                                                const float* __restrict__ rstd,
                                                const float* __restrict__ gw,
                                                const float* __restrict__ gb,
                                                u16* __restrict__ h) {
  __shared__ u16 tile[64][72];
  int b = blockIdx.z, c0 = blockIdx.y * 64, n0 = blockIdx.x * 64;
  int t = threadIdx.x;
  int cc = t >> 2, ns = (t & 3) * 16;
  int c = c0 + cc, g = c >> 4;
  float m = mean[b * 32 + g], r = rstd[b * 32 + g];
  float w = gw[c] * r;
  float bb = gb[c] - m * w;
  const float* xr = x + (((size_t)(b * 512 + c)) << 10) + n0 + ns;
#pragma unroll
  for (int u = 0; u < 16; u += 4) {
    float4 v = *(const float4*)(xr + u);
    tile[cc][ns + u + 0] = f2bf(v.x * w + bb);
    tile[cc][ns + u + 1] = f2bf(v.y * w + bb);
    tile[cc][ns + u + 2] = f2bf(v.z * w + bb);
    tile[cc][ns + u + 3] = f2bf(v.w * w + bb);
  }
  __syncthreads();
  int nn = t >> 2, cs = (t & 3) * 16;
  u16* hr = h + (((size_t)(b * 1024 + n0 + nn)) << 9) + c0 + cs;
  u16 vals[16];
#pragma unroll
  for (int u = 0; u < 16; u++) vals[u] = tile[cs + u][nn];
  *(uint4*)hr = *(uint4*)vals;
  *(uint4*)(hr + 8) = *(uint4*)(vals + 8);
}

// ---------------- QKV GEMM: A=wq[1536][512], B=h[16384][512]
__global__ __launch_bounds__(512, 1) void gemm_qkv(const u16* __restrict__ A,
                                                   const u16* __restrict__ Bn,
                                                   const float* __restrict__ bias,
                                                   u16* __restrict__ q_nc,
                                                   u16* __restrict__ k_nc,
                                                   u16* __restrict__ v) {
  __shared__ u16 lds[49152];
  int bid = blockIdx.x;               // 768: 12 mb x 64 nb, XCD n-chunked
  int xcd = bid & 7, r = bid >> 3;    // r 0..95
  int mb = r % 12, nb = xcd * 8 + r / 12;
  int m0 = mb * 128, n0 = nb * 256;
  int t = threadIdx.x, wave = t >> 6, lane = t & 63;
  int wm = wave >> 2, wn = wave & 3;
  int col = lane & 15, rq = lane >> 4;
  f32x4 acc[4][4];
  gemm_core<4, 8>(A + (size_t)m0 * 512, 512, Bn + (size_t)n0 * 512, 512,
                  lds, acc, wave, lane);
  if (mb < 8) {
    u16* dst = (mb < 4) ? q_nc : k_nc;
#pragma unroll
    for (int i = 0; i < 4; i++)
#pragma unroll
      for (int j = 0; j < 4; j++) {
        int o = m0 + wm * 64 + i * 16 + rq * 4;
        int bn = n0 + wn * 64 + j * 16 + col;
        u16 tmp[4];
#pragma unroll
        for (int rr = 0; rr < 4; rr++) tmp[rr] = f2bf(acc[i][j][rr] + bias[o + rr]);
        *(uint2*)(dst + (size_t)bn * 512 + (o & 511)) = *(uint2*)tmp;
      }
  } else {
#pragma unroll
    for (int i = 0; i < 4; i++)
#pragma unroll
      for (int j = 0; j < 4; j++)
#pragma unroll
        for (int rr = 0; rr < 4; rr++) {
          int o = m0 + wm * 64 + i * 16 + rq * 4 + rr;
          int bn = n0 + wn * 64 + j * 16 + col;
          v[(size_t)(o & 511) * 16384 + bn] = f2bf(acc[i][j][rr] + bias[o]);
        }
  }
}

// ---------------- S GEMM per b: E = exp(scale*q.k^T) bf16 (max-free softmax numerator)
__global__ __launch_bounds__(512, 1) void gemm_s(const u16* __restrict__ q_nc,
                                                 const u16* __restrict__ k_nc,
                                                 u16* __restrict__ E) {
  __shared__ u16 lds[65536];
  int bid = blockIdx.x;               // 256: 2 b per XCD, 16 tiles per b
  int xcd = bid & 7, r = bid >> 3;    // 0..31
  int b = xcd * 2 + (r & 1);
  int tile = r >> 1;                  // 0..15
  int m0 = (tile >> 2) * 256, n0 = (tile & 3) * 256;
  int t = threadIdx.x, wave = t >> 6, lane = t & 63;
  int wm = wave >> 2, wn = wave & 3;
  int col = lane & 15, rq = lane >> 4;
  f32x4 acc[8][4];
  const u16* A  = q_nc + ((size_t)(b * 1024 + m0)) * 512;
  const u16* Bn = k_nc + ((size_t)(b * 1024 + n0)) * 512;
  gemm_core<8, 8>(A, 512, Bn, 512, lds, acc, wave, lane);
  u16* Eb = E + ((size_t)b << 20);
  const float scale = 0.04419417382415922f;  // 512^-0.5
#pragma unroll
  for (int i = 0; i < 8; i++)
#pragma unroll
    for (int j = 0; j < 4; j++) {
      int ii = m0 + wm * 128 + i * 16 + rq * 4;
      int jj = n0 + wn * 64 + j * 16 + col;
#pragma unroll
      for (int rr = 0; rr < 4; rr++)
        Eb[(size_t)(ii + rr) * 1024 + jj] = f2bf(__expf(acc[i][j][rr] * scale));
    }
}

// ---------------- row inverse-sum: inv[row] = 1/sum_j E[row][j]
__global__ __launch_bounds__(256) void row_inv(const u16* __restrict__ E,
                                               float* __restrict__ inv) {
  int row = blockIdx.x * 4 + (threadIdx.x >> 6);
  int lane = threadIdx.x & 63;
  const u16* er = E + (size_t)row * 1024 + lane * 16;
  uint4 a = *(const uint4*)er;
  uint4 c = *(const uint4*)(er + 8);
  float s = 0.f;
  unsigned ws[8] = {a.x, a.y, a.z, a.w, c.x, c.y, c.z, c.w};
#pragma unroll
  for (int u = 0; u < 8; u++) {
    union { unsigned u; float f; } lo, hi;
    lo.u = ws[u] << 16; hi.u = ws[u] & 0xffff0000u;
    s += lo.f + hi.f;
  }
#pragma unroll
  for (int d = 1; d < 64; d <<= 1) s += __shfl_xor(s, d);
  if (lane == 0) inv[row] = 1.0f / s;
}

// ---------------- PV GEMM per b: O[i][c] = inv[i]*sum_j E[i][j]*v[c][j] -> o_nc[bn][c]
__global__ __launch_bounds__(512, 1) void gemm_pv(const u16* __restrict__ E,
                                                  const u16* __restrict__ v,
                                                  const float* __restrict__ inv,
                                                  u16* __restrict__ o_nc) {
  __shared__ u16 lds[49152];
  int bid = blockIdx.x;               // 256: 2 b per XCD, 8 tiles per b
  int xcd = bid & 7, r = bid >> 3;    // 0..31
  int b = xcd * 2 + (r & 1);
  int tile = r >> 1;                  // 0..7
  int m0 = (tile >> 1) * 128, n0 = (tile & 1) * 256;
  int t = threadIdx.x, wave = t >> 6, lane = t & 63;
  int wm = wave >> 2, wn = wave & 3;
  int col = lane & 15, rq = lane >> 4;
  f32x4 acc[4][4];
  const u16* A  = E + ((size_t)b << 20) + (size_t)m0 * 1024;
  const u16* Bn = v + (size_t)n0 * 16384 + ((size_t)b << 10);
  gemm_core<4, 16>(A, 1024, Bn, 16384, lds, acc, wave, lane);
#pragma unroll
  for (int i = 0; i < 4; i++)
#pragma unroll
    for (int j = 0; j < 4; j++)
#pragma unroll
      for (int rr = 0; rr < 4; rr++) {
        int ii = m0 + wm * 64 + i * 16 + rq * 4 + rr;
        int cc = n0 + wn * 64 + j * 16 + col;
        float sc = inv[(b << 10) + ii];
        o_nc[(((size_t)(b * 1024 + ii)) << 9) + cc] = f2bf(acc[i][j][rr] * sc);
      }
}

// ---------------- proj GEMM + bias + residual -> fp32 out[b][co][n]
__global__ __launch_bounds__(512, 1) void gemm_proj(const u16* __restrict__ A,
                                                    const u16* __restrict__ Bn,
                                                    const float* __restrict__ bias,
                                                    const float* __restrict__ xres,
                                                    float* __restrict__ outp) {
  __shared__ u16 lds[49152];
  int bid = blockIdx.x;               // 256: 4 mb x 64 nb, XCD n-chunked
  int xcd = bid & 7, r = bid >> 3;    // 0..31
  int mb = r % 4, nb = xcd * 8 + r / 4;
  int m0 = mb * 128, n0 = nb * 256;
  int t = threadIdx.x, wave = t >> 6, lane = t & 63;
  int wm = wave >> 2, wn = wave & 3;
  int col = lane & 15, rq = lane >> 4;
  f32x4 acc[4][4];
  gemm_core<4, 8>(A + (size_t)m0 * 512, 512, Bn + (size_t)n0 * 512, 512,
                  lds, acc, wave, lane);
#pragma unroll
  for (int i = 0; i < 4; i++)
#pragma unroll
    for (int j = 0; j < 4; j++)
#pragma unroll
      for (int rr = 0; rr < 4; rr++) {
        int co = m0 + wm * 64 + i * 16 + rq * 4 + rr;
        int bn = n0 + wn * 64 + j * 16 + col;
        int bb = bn >> 10, n = bn & 1023;
        size_t oi = (((size_t)(bb * 512 + co)) << 10) + n;
        outp[oi] = acc[i][j][rr] + bias[co] + xres[oi];
      }
}

extern "C" void kernel_launch(void* const* d_in, const int* in_sizes, int n_in,
                              void* d_out, int out_size, void* d_ws, size_t ws_size,
                              hipStream_t stream) {
  const float* x      = (const float*)d_in[0];
  const float* norm_w = (const float*)d_in[1];
  const float* norm_b = (const float*)d_in[2];
  const float* qkv_w  = (const float*)d_in[3];
  const float* qkv_b  = (const float*)d_in[4];
  const float* proj_w = (const float*)d_in[5];
  const float* proj_b = (const float*)d_in[6];
  float* out = (float*)d_out;

  char* ws = (char*)d_ws;
  size_t off = 0;
  auto alloc = [&](size_t bytes) {
    void* p = ws + off;
    off += (bytes + 255) & ~(size_t)255;
    return p;
  };
  float* mean = (float*)alloc(512 * 4);
  float* rstd = (float*)alloc(512 * 4);
  float* inv  = (float*)alloc(16384 * 4);
  u16* wq   = (u16*)alloc((size_t)1536 * 512 * 2);
  u16* wp   = (u16*)alloc((size_t)512 * 512 * 2);
  u16* h    = (u16*)alloc((size_t)16384 * 512 * 2);   // reused as o_nc after QKV GEMM
  u16* q_nc = (u16*)alloc((size_t)16384 * 512 * 2);
  u16* k_nc = (u16*)alloc((size_t)16384 * 512 * 2);
  u16* v    = (u16*)alloc((size_t)512 * 16384 * 2);
  u16* E    = (u16*)alloc((size_t)16 * 1024 * 1024 * 2);
  u16* o_nc = h;
  (void)in_sizes; (void)n_in; (void)out_size; (void)ws_size;

  gn_stats<<<512, 256, 0, stream>>>(x, mean, rstd);
  cast_bf16<<<(1536 * 512) / 1024, 256, 0, stream>>>(qkv_w, wq, 1536 * 512);
  cast_bf16<<<(512 * 512) / 1024, 256, 0, stream>>>(proj_w, wp, 512 * 512);
  gn_apply<<<dim3(16, 8, 16), 256, 0, stream>>>(x, mean, rstd, norm_w, norm_b, h);
  gemm_qkv<<<768, 512, 0, stream>>>(wq, h, qkv_b, q_nc, k_nc, v);
  gemm_s<<<256, 512, 0, stream>>>(q_nc, k_nc, E);
  row_inv<<<4096, 256, 0, stream>>>(E, inv);
  gemm_pv<<<256, 512, 0, stream>>>(E, v, inv, o_nc);
  gemm_proj<<<256, 512, 0, stream>>>(wp, o_nc, proj_b, x, out);
}